// Round 1
// baseline (246.942 us; speedup 1.0000x reference)
//
#include <hip/hip_runtime.h>
#include <hip/hip_bf16.h>

// B=8, C=64, N=4096, CQK=8. Flash-attention formulation:
//   S[n,m] = sum_q f[q,n] g[q,m]; beta = softmax_n(S); o = gamma*hv@beta + x
// ws layout: ft [B][N][8] bf16 (f transposed), gt [B][N][8] bf16, hv [B][64][N] bf16.

typedef __attribute__((ext_vector_type(4))) float f32x4;
typedef __attribute__((ext_vector_type(8))) short bf16x8;

__device__ __forceinline__ unsigned short f2bf(float f) {
  union { float f; unsigned u; } v; v.f = f;
  return (unsigned short)((v.u + 0x7FFFu + ((v.u >> 16) & 1u)) >> 16);  // RNE
}

// ---------------- projection kernel: f, g, hv from x ----------------
__global__ __launch_bounds__(256) void proj_kernel(
    const float* __restrict__ x,
    const float* __restrict__ Wq, const float* __restrict__ bq,
    const float* __restrict__ Wk, const float* __restrict__ bk,
    const float* __restrict__ Wv, const float* __restrict__ bv,
    __hip_bfloat16* __restrict__ ft,
    __hip_bfloat16* __restrict__ gt,
    __hip_bfloat16* __restrict__ hv) {
  __shared__ float xs[64][65];  // [c][p], +1 pad
  const int t = threadIdx.x;
  const int b = blockIdx.x >> 6;
  const int n0 = (blockIdx.x & 63) << 6;
  const int p = t & 63;
  const int wv = t >> 6;  // wave id 0..3, uniform per wave

#pragma unroll
  for (int r = 0; r < 16; ++r) {
    const int c = r * 4 + wv;
    xs[c][p] = x[(b * 64 + c) * 4096 + n0 + p];  // coalesced 256B per row
  }
  __syncthreads();

  float xcol[64];
#pragma unroll
  for (int c = 0; c < 64; ++c) xcol[c] = xs[c][p];  // column read, conflict-free (65 pad)

  const int ou = __builtin_amdgcn_readfirstlane(wv);  // force SGPR -> s_load for W rows
  const int n = n0 + p;

#pragma unroll
  for (int k = 0; k < 2; ++k) {  // f,g outputs: q = ou, ou+4
    const int o = ou + 4 * k;
    float aq = bq[o], ag = bk[o];
#pragma unroll
    for (int c = 0; c < 64; ++c) {
      aq = fmaf(Wq[o * 64 + c], xcol[c], aq);
      ag = fmaf(Wk[o * 64 + c], xcol[c], ag);
    }
    ft[(b * 4096 + n) * 8 + o] = __float2bfloat16(aq);
    gt[(b * 4096 + n) * 8 + o] = __float2bfloat16(ag);
  }
#pragma unroll
  for (int k = 0; k < 16; ++k) {  // hv output channels: c_out = ou + 4k
    const int o = ou + 4 * k;
    float av = bv[o];
#pragma unroll
    for (int c = 0; c < 64; ++c) av = fmaf(Wv[o * 64 + c], xcol[c], av);
    hv[(b * 64 + o) * 4096 + n] = __float2bfloat16(av);
  }
}

// ---------------- fused flash attention ----------------
// One wave = one (batch, 16-query tile). No LDS, no barriers.
// QK mfma: D[n][m] = sum_k A[n][k]B[k][m], A=f^T (k=q, zero-padded to 32), B=g.
// A/B frag: lane l holds [row/col = l&15][k = (l>>4)*8 + e] (8 contiguous k, 16B).
// C/D frag: col = l&15, row = (l>>4)*4 + r  (verified layout, learn_hip m89/m91).
__global__ __launch_bounds__(256) void attn_kernel(
    const __hip_bfloat16* __restrict__ ft,
    const __hip_bfloat16* __restrict__ gt,
    const __hip_bfloat16* __restrict__ hv,
    const float* __restrict__ x,
    const float* __restrict__ gamma,
    float* __restrict__ out) {
  const int wid = blockIdx.x * 4 + (threadIdx.x >> 6);  // 0..2047
  const int b = wid >> 8;            // 256 query tiles per batch
  const int m0 = (wid & 255) << 4;   // query tile base
  const int l = threadIdx.x & 63;
  const int lg = l >> 4;             // lane group 0..3
  const int lm = l & 15;

  const __hip_bfloat16* ftb = ft + b * 4096 * 8;
  const __hip_bfloat16* gtb = gt + b * 4096 * 8;
  const __hip_bfloat16* hb = hv + b * 64 * 4096;

  const f32x4 zf = {0.f, 0.f, 0.f, 0.f};
  bf16x8 zab = {0, 0, 0, 0, 0, 0, 0, 0};

  // Q fragment (B operand), loaded once: lanes 0..15 carry k=0..7 (=q), rest zero
  bf16x8 qf = zab;
  if (l < 16) qf = *(const bf16x8*)(gtb + (m0 + lm) * 8);

  f32x4 acc[4];
#pragma unroll
  for (int ct = 0; ct < 4; ++ct) acc[ct] = zf;
  float M = -1e30f, Lsum = 0.f;

  for (int n0 = 0; n0 < 4096; n0 += 32) {
    // ---- QK^T: S[32n][16m] in two 16x16 tiles ----
    bf16x8 af0 = zab, af1 = zab;
    if (l < 16) {
      af0 = *(const bf16x8*)(ftb + (n0 + lm) * 8);
      af1 = *(const bf16x8*)(ftb + (n0 + 16 + lm) * 8);
    }
    f32x4 s0 = __builtin_amdgcn_mfma_f32_16x16x32_bf16(af0, qf, zf, 0, 0, 0);
    f32x4 s1 = __builtin_amdgcn_mfma_f32_16x16x32_bf16(af1, qf, zf, 0, 0, 0);

    // ---- online softmax over n (rows). col m = lm is lane-local ----
    float tmax = fmaxf(fmaxf(fmaxf(s0[0], s0[1]), fmaxf(s0[2], s0[3])),
                       fmaxf(fmaxf(s1[0], s1[1]), fmaxf(s1[2], s1[3])));
    tmax = fmaxf(tmax, __shfl_xor(tmax, 16, 64));
    tmax = fmaxf(tmax, __shfl_xor(tmax, 32, 64));

    if (!__all(tmax <= M)) {  // exact skip: if no lane's max grew, scale==1
      const float Mn = fmaxf(M, tmax);
      const float sc = __expf(M - Mn);
      M = Mn;
      Lsum *= sc;
#pragma unroll
      for (int ct = 0; ct < 4; ++ct) acc[ct] *= sc;
    }

    float p[8];
    p[0] = __expf(s0[0] - M); p[1] = __expf(s0[1] - M);
    p[2] = __expf(s0[2] - M); p[3] = __expf(s0[3] - M);
    p[4] = __expf(s1[0] - M); p[5] = __expf(s1[1] - M);
    p[6] = __expf(s1[2] - M); p[7] = __expf(s1[3] - M);
    float rs = ((p[0] + p[1]) + (p[2] + p[3])) + ((p[4] + p[5]) + (p[6] + p[7]));
    rs += __shfl_xor(rs, 16, 64);
    rs += __shfl_xor(rs, 32, 64);
    Lsum += rs;

    // ---- assemble PV B-fragment: pb[e] = P[n_local = lg*8+e][m=lm] ----
    // source lane = lm + 16*((lg*2 + (w>>1))&3); t(=frag half) = lg>>1 selects lo/hi
    unsigned q01 = (unsigned)f2bf(p[0]) | ((unsigned)f2bf(p[1]) << 16);  // t0,r01
    unsigned q23 = (unsigned)f2bf(p[2]) | ((unsigned)f2bf(p[3]) << 16);  // t0,r23
    unsigned q45 = (unsigned)f2bf(p[4]) | ((unsigned)f2bf(p[5]) << 16);  // t1,r01
    unsigned q67 = (unsigned)f2bf(p[6]) | ((unsigned)f2bf(p[7]) << 16);  // t1,r23
    unsigned bw[4];
#pragma unroll
    for (int w = 0; w < 4; ++w) {
      const int srcl = lm + 16 * ((lg * 2 + (w >> 1)) & 3);
      const unsigned vlo = (unsigned)__shfl((int)((w & 1) ? q23 : q01), srcl, 64);
      const unsigned vhi = (unsigned)__shfl((int)((w & 1) ? q67 : q45), srcl, 64);
      bw[w] = (lg >= 2) ? vhi : vlo;
    }
    union { unsigned u[4]; bf16x8 v; } pu;
    pu.u[0] = bw[0]; pu.u[1] = bw[1]; pu.u[2] = bw[2]; pu.u[3] = bw[3];
    const bf16x8 pb = pu.v;

    // ---- PV: acc[ct] += V_tile[16c x 32n] @ P[32n x 16m] ----
    const __hip_bfloat16* hp = hb + n0 + lg * 8;
#pragma unroll
    for (int ct = 0; ct < 4; ++ct) {
      const bf16x8 va = *(const bf16x8*)(hp + (ct * 16 + lm) * 4096);
      acc[ct] = __builtin_amdgcn_mfma_f32_16x16x32_bf16(va, pb, acc[ct], 0, 0, 0);
    }
  }

  // ---- epilogue: out = gamma * acc / L + x ----
  const float inv = gamma[0] / Lsum;
  const float* xb = x + b * 64 * 4096;
  float* ob = out + b * 64 * 4096;
#pragma unroll
  for (int ct = 0; ct < 4; ++ct) {
#pragma unroll
    for (int r = 0; r < 4; ++r) {
      const int c = ct * 16 + lg * 4 + r;
      const int idx = c * 4096 + m0 + lm;
      ob[idx] = fmaf(acc[ct][r], inv, xb[idx]);
    }
  }
}

extern "C" void kernel_launch(void* const* d_in, const int* in_sizes, int n_in,
                              void* d_out, int out_size, void* d_ws, size_t ws_size,
                              hipStream_t stream) {
  const float* x = (const float*)d_in[0];
  const float* Wq = (const float*)d_in[1];
  const float* bq = (const float*)d_in[2];
  const float* Wk = (const float*)d_in[3];
  const float* bk = (const float*)d_in[4];
  const float* Wv = (const float*)d_in[5];
  const float* bv = (const float*)d_in[6];
  const float* gamma = (const float*)d_in[7];
  float* out = (float*)d_out;

  __hip_bfloat16* ft = (__hip_bfloat16*)d_ws;          // [8][4096][8]
  __hip_bfloat16* gt = ft + 8 * 4096 * 8;              // [8][4096][8]
  __hip_bfloat16* hv = gt + 8 * 4096 * 8;              // [8][64][4096]

  hipLaunchKernelGGL(proj_kernel, dim3(512), dim3(256), 0, stream,
                     x, Wq, bq, Wk, bk, Wv, bv, ft, gt, hv);
  hipLaunchKernelGGL(attn_kernel, dim3(512), dim3(256), 0, stream,
                     ft, gt, hv, x, gamma, out);
}

// Round 2
// 148.014 us; speedup vs baseline: 1.6684x; 1.6684x over previous
//
#include <hip/hip_runtime.h>
#include <hip/hip_bf16.h>

// B=8, C=64, N=4096, CQK=8. Flash-attention formulation:
//   S[n,m] = sum_q f[q,n] g[q,m]; beta = softmax_n(S); o = gamma*hv@beta + x
// ws: ft [B][N][8] bf16, gt [B][N][8] bf16, hv [B][64][N] bf16.

typedef __attribute__((ext_vector_type(16))) float f32x16;
typedef __attribute__((ext_vector_type(8))) short bf16x8;

__device__ __forceinline__ unsigned pk_bf16(float lo, float hi) {
  union { __hip_bfloat16 h; unsigned short u; } a, b;
  a.h = __float2bfloat16(lo); b.h = __float2bfloat16(hi);
  return (unsigned)a.u | ((unsigned)b.u << 16);
}

__device__ __forceinline__ void plane32_swap(unsigned& a, unsigned& b) {
  asm("v_permlane32_swap_b32 %0, %1" : "+v"(a), "+v"(b));
}

// ---------------- projection: f, g, hv from x ----------------
// 512 blocks x 512 threads. Block = (batch, 64-position tile).
// Thread (p, grp): computes f[grp], g[grp], hv[grp + 8k] for position p.
__global__ __launch_bounds__(512) void proj_kernel(
    const float* __restrict__ x,
    const float* __restrict__ Wq, const float* __restrict__ bq,
    const float* __restrict__ Wk, const float* __restrict__ bk,
    const float* __restrict__ Wv, const float* __restrict__ bv,
    __hip_bfloat16* __restrict__ ft,
    __hip_bfloat16* __restrict__ gt,
    __hip_bfloat16* __restrict__ hv) {
  __shared__ float xs[64][65];
  const int t = threadIdx.x;
  const int p = t & 63;
  const int grp = t >> 6;  // 0..7, wave-uniform
  const int b = blockIdx.x >> 6;
  const int n0 = (blockIdx.x & 63) << 6;

#pragma unroll
  for (int r = 0; r < 8; ++r) {
    const int c = grp * 8 + r;
    xs[c][p] = x[(b * 64 + c) * 4096 + n0 + p];  // coalesced
  }
  __syncthreads();

  float xcol[64];
#pragma unroll
  for (int c = 0; c < 64; ++c) xcol[c] = xs[c][p];

  const int o0 = __builtin_amdgcn_readfirstlane(grp);  // SGPR -> s_load W rows
  const int n = n0 + p;

  {
    float aq = bq[o0], ag = bk[o0];
#pragma unroll
    for (int c = 0; c < 64; ++c) {
      aq = fmaf(Wq[o0 * 64 + c], xcol[c], aq);
      ag = fmaf(Wk[o0 * 64 + c], xcol[c], ag);
    }
    ft[(b * 4096 + n) * 8 + o0] = __float2bfloat16(aq);
    gt[(b * 4096 + n) * 8 + o0] = __float2bfloat16(ag);
  }
#pragma unroll
  for (int k = 0; k < 8; ++k) {
    const int o = o0 + 8 * k;
    float av = bv[o];
#pragma unroll
    for (int c = 0; c < 64; ++c) av = fmaf(Wv[o * 64 + c], xcol[c], av);
    hv[(b * 64 + o) * 4096 + n] = __float2bfloat16(av);
  }
}

// ---------------- fused flash attention, 32x32 MFMA + split-K ----------------
// Block = (batch, 32-query tile); 4 waves, wave wv handles keys [wv*1024, wv*1024+1024).
// QK: mfma_32x32x16(A=f^T, B=g), K=16 (q padded 8->16 with zeros in lanes>=32).
//   A-frag: lane l: row n=l&31, k=(l>>5)*8+e.  D: col m=l&31, row n=(j&3)+8*(j>>2)+4*(l>>5).
// P redistribution to PV B-frag via v_permlane32_swap_b32 (2 per 16-k chunk).
// PV: acc[ct] += V[ct*32..+31][n-chunk] @ P, 32x32x16 per chunk. Cross-wave combine in LDS.
__global__ __launch_bounds__(256, 4) void attn_kernel(
    const __hip_bfloat16* __restrict__ ft,
    const __hip_bfloat16* __restrict__ gt,
    const __hip_bfloat16* __restrict__ hv,
    const float* __restrict__ x,
    const float* __restrict__ gamma,
    float* __restrict__ out) {
  __shared__ float lacc[4][32][64];
  __shared__ float lML[4][2][64];

  const int wv = threadIdx.x >> 6;
  const int l = threadIdx.x & 63;
  const int hi = l >> 5;
  const int lm = l & 31;
  const int b = blockIdx.x >> 7;         // 128 query tiles per batch
  const int m0 = (blockIdx.x & 127) << 5;

  const __hip_bfloat16* ftb = ft + b * 4096 * 8;
  const __hip_bfloat16* gtb = gt + b * 4096 * 8;
  const __hip_bfloat16* hb = hv + b * 64 * 4096;

  const bf16x8 zab = {0, 0, 0, 0, 0, 0, 0, 0};
  f32x16 zf16;
#pragma unroll
  for (int j = 0; j < 16; ++j) zf16[j] = 0.f;

  bf16x8 gf = zab;
  if (l < 32) gf = *(const bf16x8*)(gtb + (m0 + lm) * 8);

  f32x16 acc0 = zf16, acc1 = zf16;
  float M = -1e30f, Lsum = 0.f;

  const int n_base = wv << 10;
  for (int it = 0; it < 32; ++it) {
    const int n0 = n_base + (it << 5);

    bf16x8 af = zab;
    if (l < 32) af = *(const bf16x8*)(ftb + (n0 + lm) * 8);
    f32x16 s = __builtin_amdgcn_mfma_f32_32x32x16_bf16(af, gf, zf16, 0, 0, 0);

    // column max: 16 rows in-lane + partner half via xor-32
    float tmax = fmaxf(fmaxf(fmaxf(s[0], s[1]), fmaxf(s[2], s[3])),
                       fmaxf(fmaxf(s[4], s[5]), fmaxf(s[6], s[7])));
    tmax = fmaxf(tmax, fmaxf(fmaxf(fmaxf(s[8], s[9]), fmaxf(s[10], s[11])),
                             fmaxf(fmaxf(s[12], s[13]), fmaxf(s[14], s[15]))));
    tmax = fmaxf(tmax, __shfl_xor(tmax, 32));

    if (!__all(tmax <= M)) {  // exact skip when no column max grew
      const float Mn = fmaxf(M, tmax);
      const float sc = __expf(M - Mn);
      M = Mn;
      Lsum *= sc;
      acc0 *= sc;
      acc1 *= sc;
    }

    float p[16];
#pragma unroll
    for (int j = 0; j < 16; ++j) p[j] = __expf(s[j] - M);
    float rs = 0.f;
#pragma unroll
    for (int j = 0; j < 16; ++j) rs += p[j];
    Lsum += rs + __shfl_xor(rs, 32);

    // pack consecutive-n pairs: w[j] = (n = base+2j of this half)
    unsigned w0 = pk_bf16(p[0], p[1]),  w1 = pk_bf16(p[2], p[3]);
    unsigned w2 = pk_bf16(p[4], p[5]),  w3 = pk_bf16(p[6], p[7]);
    unsigned w4 = pk_bf16(p[8], p[9]),  w5 = pk_bf16(p[10], p[11]);
    unsigned w6 = pk_bf16(p[12], p[13]), w7 = pk_bf16(p[14], p[15]);
    // redistribute into PV B-fragment k-order
    plane32_swap(w0, w2);  // -> chunk0 words 0,2
    plane32_swap(w1, w3);  // -> chunk0 words 1,3
    plane32_swap(w4, w6);  // -> chunk1 words 0,2
    plane32_swap(w5, w7);  // -> chunk1 words 1,3
    union { unsigned u[4]; bf16x8 v; } pb0, pb1;
    pb0.u[0] = w0; pb0.u[1] = w1; pb0.u[2] = w2; pb0.u[3] = w3;
    pb1.u[0] = w4; pb1.u[1] = w5; pb1.u[2] = w6; pb1.u[3] = w7;

    // PV: A-frag lane l: row c = ct*32+lm, k = n = ck*16 + hi*8 + e (contiguous)
    const __hip_bfloat16* hp = hb + n0 + hi * 8;
    const bf16x8 va00 = *(const bf16x8*)(hp + lm * 4096);
    const bf16x8 va01 = *(const bf16x8*)(hp + lm * 4096 + 16);
    const bf16x8 va10 = *(const bf16x8*)(hp + (32 + lm) * 4096);
    const bf16x8 va11 = *(const bf16x8*)(hp + (32 + lm) * 4096 + 16);
    acc0 = __builtin_amdgcn_mfma_f32_32x32x16_bf16(va00, pb0.v, acc0, 0, 0, 0);
    acc0 = __builtin_amdgcn_mfma_f32_32x32x16_bf16(va01, pb1.v, acc0, 0, 0, 0);
    acc1 = __builtin_amdgcn_mfma_f32_32x32x16_bf16(va10, pb0.v, acc1, 0, 0, 0);
    acc1 = __builtin_amdgcn_mfma_f32_32x32x16_bf16(va11, pb1.v, acc1, 0, 0, 0);
  }

  // ---- cross-wave combine ----
#pragma unroll
  for (int j = 0; j < 16; ++j) {
    lacc[wv][j][l] = acc0[j];
    lacc[wv][16 + j][l] = acc1[j];
  }
  lML[wv][0][l] = M;
  lML[wv][1][l] = Lsum;
  __syncthreads();

  const float M0 = lML[0][0][l], M1 = lML[1][0][l], M2 = lML[2][0][l], M3 = lML[3][0][l];
  const float Mg = fmaxf(fmaxf(M0, M1), fmaxf(M2, M3));
  const float s0 = __expf(M0 - Mg), s1 = __expf(M1 - Mg);
  const float s2 = __expf(M2 - Mg), s3 = __expf(M3 - Mg);
  const float Lg = s0 * lML[0][1][l] + s1 * lML[1][1][l] + s2 * lML[2][1][l] + s3 * lML[3][1][l];
  const float scale = gamma[0] / Lg;

  const float* xb = x + b * 64 * 4096;
  float* ob = out + b * 64 * 4096;
#pragma unroll
  for (int jj = 0; jj < 8; ++jj) {
    const int jp = wv * 8 + jj;  // 0..31: which acc register
    const int ct = jp >> 4;
    const int j = jp & 15;
    const float v = s0 * lacc[0][jp][l] + s1 * lacc[1][jp][l] +
                    s2 * lacc[2][jp][l] + s3 * lacc[3][jp][l];
    const int c = ct * 32 + (j & 3) + 8 * (j >> 2) + 4 * hi;
    const int idx = c * 4096 + m0 + lm;
    ob[idx] = fmaf(v, scale, xb[idx]);
  }
}

extern "C" void kernel_launch(void* const* d_in, const int* in_sizes, int n_in,
                              void* d_out, int out_size, void* d_ws, size_t ws_size,
                              hipStream_t stream) {
  const float* x = (const float*)d_in[0];
  const float* Wq = (const float*)d_in[1];
  const float* bq = (const float*)d_in[2];
  const float* Wk = (const float*)d_in[3];
  const float* bk = (const float*)d_in[4];
  const float* Wv = (const float*)d_in[5];
  const float* bv = (const float*)d_in[6];
  const float* gamma = (const float*)d_in[7];
  float* out = (float*)d_out;

  __hip_bfloat16* ft = (__hip_bfloat16*)d_ws;          // [8][4096][8]
  __hip_bfloat16* gt = ft + 8 * 4096 * 8;              // [8][4096][8]
  __hip_bfloat16* hv = gt + 8 * 4096 * 8;              // [8][64][4096]

  hipLaunchKernelGGL(proj_kernel, dim3(512), dim3(512), 0, stream,
                     x, Wq, bq, Wk, bk, Wv, bv, ft, gt, hv);
  hipLaunchKernelGGL(attn_kernel, dim3(1024), dim3(256), 0, stream,
                     ft, gt, hv, x, gamma, out);
}